// Round 1
// 1353.710 us; speedup vs baseline: 1.2352x; 1.2352x over previous
//
#include <hip/hip_runtime.h>
#include <hip/hip_bf16.h>

#define VV 100000
#define EE 128
#define BB 2048
#define BM 128
#define BN 128
#define LDK 136   // 128 + 8 pad (bf16 elems) to break power-of-2 LDS strides
#define NWG (((VV + BN - 1) / BN) * (BB / BM))   // 782*16 = 12512, % 8 == 0

typedef __bf16 bf16x8 __attribute__((ext_vector_type(8)));
typedef float  f32x4  __attribute__((ext_vector_type(4)));

__device__ __forceinline__ unsigned short f2bf(float f) {
    union { float f; unsigned u; } x; x.f = f;
    unsigned r = x.u + 0x7fffu + ((x.u >> 16) & 1u);  // RNE
    return (unsigned short)(r >> 16);
}

// emb[b][e] = W_center[e][idx[b]] + b_center[e], stored as bf16 bits.
// Also zero the per-row sum-exp accumulators (ws is re-poisoned each call).
__global__ __launch_bounds__(256) void prep_kernel(
    const int* __restrict__ idx, const float* __restrict__ Wc,
    const float* __restrict__ bc, unsigned short* __restrict__ embB,
    float* __restrict__ s)
{
    int gid = blockIdx.x * 256 + threadIdx.x;   // 0 .. 2048*128-1
    int b = gid >> 7, e = gid & 127;
    float v = Wc[(size_t)e * VV + idx[b]] + bc[e];
    embB[gid] = f2bf(v);
    if (gid < BB) s[gid] = 0.0f;
}

__global__ __launch_bounds__(256) void lse_kernel(
    const float* __restrict__ s, float* __restrict__ lse)
{
    int gid = blockIdx.x * 256 + threadIdx.x;
    if (gid < BB) lse[gid] = logf(s[gid]);
}

// 128x128 output tile per block; K=128, no K loop.
// A (emb, bf16) read per-fragment straight from global — embB is 512 KB and
// L2-resident, so staging it in LDS only cost occupancy. Only B (W_out,
// f32->bf16 convert) is staged in LDS: 35 KB -> 4 blocks/CU (was 2).
// Bijective XCD swizzle: all 16 row-blocks sharing one W_out vocab tile land
// on the same XCD's L2 (kills the 4x W_out overfetch seen in FETCH_SIZE).
// PASS 1: accumulate per-row sum(exp(logit)) into global s[] (no stores).
// PASS 2: out[b][v] = logit + b_out[v] - lse[b].
template <int PASS>
__global__ __launch_bounds__(256, 4) void gemm_kernel(
    const unsigned short* __restrict__ embB,   // [B][128] bf16 bits
    const float*  __restrict__ Wout,           // [V][128]
    const float*  __restrict__ bout,           // [V]
    float* __restrict__ sumexp,                // [B]   (pass 1)
    const float* __restrict__ lse,             // [B]   (pass 2)
    float* __restrict__ out)                   // [B][V] (pass 2)
{
    __shared__ unsigned short sB[BN * LDK];    // 34816 B
    __shared__ float sSum[BM];                 // 512 B

    const int tid = threadIdx.x;
    // XCD-aware bijective remap (nwg = 12512 = 8 * 1564): hw blocks round-robin
    // XCDs by linear id; give XCD k the contiguous wgid range [k*1564, (k+1)*1564).
    const int bid   = blockIdx.y * gridDim.x + blockIdx.x;
    const int wgid  = (bid & 7) * (NWG / 8) + (bid >> 3);
    const int rbase = (wgid & 15) * BM;        // 16 row tiles (x-fastest)
    const int vbase = (wgid >> 4) * BN;        // 782 vocab tiles

    if (PASS == 1 && tid < BM) sSum[tid] = 0.0f;

    // stage B: 128 W_out rows x 128 f32 (32 float4/row), convert to bf16
    #pragma unroll
    for (int it = 0; it < 16; ++it) {
        int k4 = tid + it * 256;               // 0..4095
        int row = k4 >> 5, c4 = k4 & 31;
        int v = vbase + row;
        float4 w = make_float4(0.f, 0.f, 0.f, 0.f);
        if (v < VV) w = *(const float4*)(Wout + (size_t)v * EE + c4 * 4);
        ushort4 h;
        h.x = f2bf(w.x); h.y = f2bf(w.y); h.z = f2bf(w.z); h.w = f2bf(w.w);
        *(ushort4*)(sB + row * LDK + c4 * 4) = h;
    }
    __syncthreads();

    const int lane = tid & 63;
    const int wave = tid >> 6;
    const int wr   = (wave >> 1) * 64;
    const int wc   = (wave & 1) * 64;
    const int l16  = lane & 15;
    const int quad = lane >> 4;

    f32x4 acc[4][4];
    #pragma unroll
    for (int i = 0; i < 4; ++i)
        #pragma unroll
        for (int j = 0; j < 4; ++j)
            acc[i][j] = (f32x4){0.f, 0.f, 0.f, 0.f};

    // A[m=l16][k=quad*8+jj] from global / B[n=l16][k=...] from LDS -> A.B^T
    #pragma unroll
    for (int ks = 0; ks < 4; ++ks) {
        bf16x8 a[4], b[4];
        #pragma unroll
        for (int i = 0; i < 4; ++i)
            a[i] = *(const bf16x8*)(embB + (size_t)(rbase + wr + i * 16 + l16) * EE
                                         + ks * 32 + quad * 8);
        #pragma unroll
        for (int j = 0; j < 4; ++j)
            b[j] = *(const bf16x8*)(sB + (wc + j * 16 + l16) * LDK + ks * 32 + quad * 8);
        #pragma unroll
        for (int i = 0; i < 4; ++i)
            #pragma unroll
            for (int j = 0; j < 4; ++j)
                acc[i][j] = __builtin_amdgcn_mfma_f32_16x16x32_bf16(a[i], b[j], acc[i][j], 0, 0, 0);
    }

    // C/D layout (verified m89/m91): col = lane&15, row = quad*4 + reg
    if (PASS == 1) {
        #pragma unroll
        for (int i = 0; i < 4; ++i) {
            float rs[4] = {0.f, 0.f, 0.f, 0.f};
            #pragma unroll
            for (int j = 0; j < 4; ++j) {
                int v = vbase + wc + j * 16 + l16;
                if (v < VV) {
                    float bo = bout[v];
                    #pragma unroll
                    for (int r = 0; r < 4; ++r)
                        rs[r] += __expf(acc[i][j][r] + bo);
                }
            }
            #pragma unroll
            for (int r = 0; r < 4; ++r) {
                float t = rs[r];
                t += __shfl_xor(t, 1);
                t += __shfl_xor(t, 2);
                t += __shfl_xor(t, 4);
                t += __shfl_xor(t, 8);
                if (l16 == 0)
                    atomicAdd(&sSum[wr + i * 16 + quad * 4 + r], t);
            }
        }
        __syncthreads();
        if (tid < BM) atomicAdd(&sumexp[rbase + tid], sSum[tid]);
    } else {
        #pragma unroll
        for (int i = 0; i < 4; ++i) {
            int row0 = rbase + wr + i * 16 + quad * 4;
            #pragma unroll
            for (int r = 0; r < 4; ++r) {
                float l = lse[row0 + r];
                #pragma unroll
                for (int j = 0; j < 4; ++j) {
                    int v = vbase + wc + j * 16 + l16;
                    if (v < VV)
                        out[(size_t)(row0 + r) * VV + v] = acc[i][j][r] + bout[v] - l;
                }
            }
        }
    }
}

extern "C" void kernel_launch(void* const* d_in, const int* in_sizes, int n_in,
                              void* d_out, int out_size, void* d_ws, size_t ws_size,
                              hipStream_t stream) {
    const int*   idx  = (const int*)d_in[0];
    const float* Wc   = (const float*)d_in[1];
    const float* bc   = (const float*)d_in[2];
    const float* Wout = (const float*)d_in[3];
    const float* bout = (const float*)d_in[4];
    float* out = (float*)d_out;

    unsigned short* embB = (unsigned short*)d_ws;                 // 512 KB
    float* s   = (float*)((char*)d_ws + BB * EE * sizeof(unsigned short));
    float* lse = (float*)((char*)s + BB * sizeof(float));

    prep_kernel<<<(BB * EE) / 256, 256, 0, stream>>>(idx, Wc, bc, embB, s);

    dim3 grid(BB / BM, (VV + BN - 1) / BN);   // (16, 782)
    gemm_kernel<1><<<grid, 256, 0, stream>>>(embB, Wout, bout, s, nullptr, nullptr);
    lse_kernel<<<(BB + 255) / 256, 256, 0, stream>>>(s, lse);
    gemm_kernel<2><<<grid, 256, 0, stream>>>(embB, Wout, bout, nullptr, lse, out);
}